// Round 18
// baseline (46.354 us; speedup 1.0000x reference)
//
#include <hip/hip_runtime.h>

#define BB 8
#define HH 512
#define WW 512
#define HW (HH * WW)

typedef float f32x2 __attribute__((ext_vector_type(2)));
typedef float f32x4 __attribute__((ext_vector_type(4)));

__device__ __forceinline__ int reflect512(int v) {
    v = v < 0 ? -v : v;
    return v >= 512 ? 1022 - v : v;
}

// unnormalized 1-D spatial gaussian (sigma=21); out-of-window -> 0 (mask)
__device__ __forceinline__ float swx(int dx) {
    const float SW[7] = {0.98984784f, 0.99547514f, 0.99886688f, 1.0f,
                         0.99886688f, 0.99547514f, 0.98984784f};
    return (dx < -3 || dx > 3) ? 0.0f : SW[dx + 3];
}

// exp(-0.005*d2) ~= 1 + C1*d2 + C2*d2^2, |err| <= 1.5e-5 for d<=3 (R5-proven)
#define C1S (-5.0e-3f)
#define C2S (1.25e-5f)
// log2 of spatial gaussian: ls(dx) = LK*dx^2, LK = -0.5/21^2*log2(e)
#define LK  (-0.0016357083f)

// one staged row: 9 dwordx4 -> 6 column pairs x 3 channels
__device__ __forceinline__ void loadrow(const float* __restrict__ p0,
                                        const float* __restrict__ p1,
                                        const float* __restrict__ p2,
                                        int rb, f32x2 (&q)[6][3]) {
    f32x4 a0 = *(const f32x4*)(p0 + rb), b0 = *(const f32x4*)(p0 + rb + 4),
          c0 = *(const f32x4*)(p0 + rb + 8);
    f32x4 a1 = *(const f32x4*)(p1 + rb), b1 = *(const f32x4*)(p1 + rb + 4),
          c1 = *(const f32x4*)(p1 + rb + 8);
    f32x4 a2 = *(const f32x4*)(p2 + rb), b2 = *(const f32x4*)(p2 + rb + 4),
          c2 = *(const f32x4*)(p2 + rb + 8);
    q[0][0]=(f32x2){a0.x,a0.y}; q[1][0]=(f32x2){a0.z,a0.w};
    q[2][0]=(f32x2){b0.x,b0.y}; q[3][0]=(f32x2){b0.z,b0.w};
    q[4][0]=(f32x2){c0.x,c0.y}; q[5][0]=(f32x2){c0.z,c0.w};
    q[0][1]=(f32x2){a1.x,a1.y}; q[1][1]=(f32x2){a1.z,a1.w};
    q[2][1]=(f32x2){b1.x,b1.y}; q[3][1]=(f32x2){b1.z,b1.w};
    q[4][1]=(f32x2){c1.x,c1.y}; q[5][1]=(f32x2){c1.z,c1.w};
    q[0][2]=(f32x2){a2.x,a2.y}; q[1][2]=(f32x2){a2.z,a2.w};
    q[2][2]=(f32x2){b2.x,b2.y}; q[3][2]=(f32x2){b2.z,b2.w};
    q[4][2]=(f32x2){c2.x,c2.y}; q[5][2]=(f32x2){c2.z,c2.w};
}

// all 16 active (k, pair) taps of one output row; wj is a runtime scalar
__device__ __forceinline__ void rowtaps(float wj, const f32x2 (&q)[6][3],
                                        const float (&ccr)[3][4],
                                        f32x2 (&ar)[4][4]) {
    const float wjC2 = wj * C2S, wjC1 = wj * C1S;
    const f32x2 A2 = {wjC2, wjC2}, A1 = {wjC1, wjC1}, A0 = {wj, wj};
    #pragma unroll
    for (int k = 0; k < 4; ++k) {
        #pragma unroll
        for (int P = 0; P < 6; ++P) {
            const float wlo = swx(2 * P - 4 - k);
            const float whi = swx(2 * P - 3 - k);
            if (wlo == 0.f && whi == 0.f) continue;      // pruned (compile-time)
            const f32x2 WC = {wlo, whi};                 // sgpr-pair constant
            const float k0 = ccr[0][k], k1 = ccr[1][k], k2 = ccr[2][k];
            float dlo = fabsf(q[P][0].x - k0) + fabsf(q[P][1].x - k1) + fabsf(q[P][2].x - k2);
            float dhi = fabsf(q[P][0].y - k0) + fabsf(q[P][1].y - k1) + fabsf(q[P][2].y - k2);
            f32x2 dp = {dlo, dhi};
            f32x2 z  = dp * dp;                          // pk_mul
            f32x2 w  = ((A2 * z + A1) * z + A0) * WC;    // 2x pk_fma + pk_mul
            ar[k][0] += w * q[P][0];
            ar[k][1] += w * q[P][1];
            ar[k][2] += w * q[P][2];
            ar[k][3] += w;
        }
    }
}

// 2 rows x 4 cols = 8 px/thread; r-loop ROLLED (code ~9KB vs 36KB unrolled)
// to stay I$-resident — the hypothesis under test for the persistent ~40%
// VALU idle. Border blocks run FIRST so the tail is uniform interior work.
__global__ __launch_bounds__(256) void bilateral_r18(const float* __restrict__ in,
                                                     float* __restrict__ out) {
    const int blk = blockIdx.x;
    if (blk >= 128) {
        const int iblk = blk - 128;
        // XCD swizzle: iblk%8 = XCD -> XCD k walks image k in y-order
        const int b   = iblk & 7;
        const int rp2 = iblk >> 3;                // 0..127
        const int sub = threadIdx.x >> 7;         // 0..1
        const int c   = threadIdx.x & 127;
        if (c == 0 || c == 127) return;           // handled by border blocks
        const int y0 = rp2 * 4 + sub * 2;         // rows y0, y0+1
        const int x0 = 4 * c;                     // cols x0..x0+3
        const int xl = x0 - 4;                    // leftmost loaded col (16B aligned)

        const float* __restrict__ p0 = in + (size_t)(3 * b) * HW;
        const float* __restrict__ p1 = p0 + HW;
        const float* __restrict__ p2 = p1 + HW;

        float cc0[3][4], cc1[3][4];
        {
            const int cb = y0 * WW + x0;
            f32x4 C0 = *(const f32x4*)(p0 + cb);
            f32x4 C1 = *(const f32x4*)(p1 + cb);
            f32x4 C2 = *(const f32x4*)(p2 + cb);
            cc0[0][0]=C0.x; cc0[0][1]=C0.y; cc0[0][2]=C0.z; cc0[0][3]=C0.w;
            cc0[1][0]=C1.x; cc0[1][1]=C1.y; cc0[1][2]=C1.z; cc0[1][3]=C1.w;
            cc0[2][0]=C2.x; cc0[2][1]=C2.y; cc0[2][2]=C2.z; cc0[2][3]=C2.w;
            f32x4 D0 = *(const f32x4*)(p0 + cb + WW);
            f32x4 D1 = *(const f32x4*)(p1 + cb + WW);
            f32x4 D2 = *(const f32x4*)(p2 + cb + WW);
            cc1[0][0]=D0.x; cc1[0][1]=D0.y; cc1[0][2]=D0.z; cc1[0][3]=D0.w;
            cc1[1][0]=D1.x; cc1[1][1]=D1.y; cc1[1][2]=D1.z; cc1[1][3]=D1.w;
            cc1[2][0]=D2.x; cc1[2][1]=D2.y; cc1[2][2]=D2.z; cc1[2][3]=D2.w;
        }

        f32x2 acc0[4][4], acc1[4][4];
        #pragma unroll
        for (int k = 0; k < 4; ++k)
            #pragma unroll
            for (int v = 0; v < 4; ++v) {
                acc0[k][v] = (f32x2){0.f, 0.f};
                acc1[k][v] = (f32x2){0.f, 0.f};
            }

        f32x2 q[6][3];

        // peel t=0: staged row y0-3, feeds row0 only (weight index 0 -> S3)
        loadrow(p0, p1, p2, reflect512(y0 - 3) * WW + xl, q);
        rowtaps(0.98984784f, q, cc0, acc0);

        // core t=1..6: both rows valid; wj computed arithmetically (exact)
        #pragma unroll 1
        for (int t = 1; t < 7; ++t) {
            loadrow(p0, p1, p2, reflect512(y0 - 3 + t) * WW + xl, q);
            const float f0 = (float)(t - 3);
            const float f1 = (float)(t - 4);
            const float wj0 = __builtin_amdgcn_exp2f(LK * f0 * f0);
            const float wj1 = __builtin_amdgcn_exp2f(LK * f1 * f1);
            rowtaps(wj0, q, cc0, acc0);
            rowtaps(wj1, q, cc1, acc1);
        }

        // peel t=7: staged row y0+4, feeds row1 only (weight index 6 -> S3)
        loadrow(p0, p1, p2, reflect512(y0 + 4) * WW + xl, q);
        rowtaps(0.98984784f, q, cc1, acc1);

        #pragma unroll
        for (int row = 0; row < 2; ++row) {
            f32x2 (&ar)[4][4] = row ? acc1 : acc0;
            f32x4 o0, o1, o2;
            #pragma unroll
            for (int k = 0; k < 4; ++k) {
                const float inv = 1.0f / (ar[k][3].x + ar[k][3].y);
                const float v0 = (ar[k][0].x + ar[k][0].y) * inv;
                const float v1 = (ar[k][1].x + ar[k][1].y) * inv;
                const float v2 = (ar[k][2].x + ar[k][2].y) * inv;
                if (k == 0) { o0.x = v0; o1.x = v1; o2.x = v2; }
                if (k == 1) { o0.y = v0; o1.y = v1; o2.y = v2; }
                if (k == 2) { o0.z = v0; o1.z = v1; o2.z = v2; }
                if (k == 3) { o0.w = v0; o1.w = v1; o2.w = v2; }
            }
            size_t ob = (size_t)(3 * b) * HW + (size_t)(y0 + row) * WW + x0;
            *(f32x4*)(out + ob)        = o0;
            *(f32x4*)(out + ob + HW)   = o1;
            *(f32x4*)(out + ob + 2*HW) = o2;
        }
    } else {
        // ---- border path FIRST: columns {0..3, 508..511}, all rows/batches ----
        int idx  = blk * 256 + threadIdx.x;   // exactly 32768
        int ci   = idx & 7;
        int rest = idx >> 3;
        int y = rest & 511;
        int b = rest >> 9;
        int x = ci < 4 ? ci : 504 + ci;

        const float* __restrict__ p0 = in + (size_t)(3 * b) * HW;
        const float* __restrict__ p1 = p0 + HW;
        const float* __restrict__ p2 = p1 + HW;
        int cidx = y * WW + x;
        float c0 = p0[cidx], c1 = p1[cidx], c2 = p2[cidx];
        float n0 = 0.f, n1 = 0.f, n2 = 0.f, dn = 0.f;
        #pragma unroll
        for (int dy = 0; dy < 7; ++dy) {
            int rbase = reflect512(y + dy - 3) * WW;
            float wy = swx(dy - 3);
            #pragma unroll
            for (int dx = 0; dx < 7; ++dx) {
                int o = rbase + reflect512(x + dx - 3);
                float q0 = p0[o], q1 = p1[o], q2 = p2[o];
                float d  = fabsf(q0 - c0) + fabsf(q1 - c1) + fabsf(q2 - c2);
                float d2 = d * d;
                float w  = wy * swx(dx - 3) * fmaf(fmaf(C2S, d2, C1S), d2, 1.0f);
                n0 += w * q0; n1 += w * q1; n2 += w * q2; dn += w;
            }
        }
        float inv = 1.0f / dn;
        size_t ob = (size_t)(3 * b) * HW + cidx;
        out[ob] = n0 * inv; out[ob + HW] = n1 * inv; out[ob + 2 * HW] = n2 * inv;
    }
}

extern "C" void kernel_launch(void* const* d_in, const int* in_sizes, int n_in,
                              void* d_out, int out_size, void* d_ws, size_t ws_size,
                              hipStream_t stream) {
    const float* in = (const float*)d_in[0];
    float* out = (float*)d_out;
    // 128 border blocks first, then 1024 interior (8 img x 128 row-quads)
    int blocks = 128 + 1024;
    bilateral_r18<<<blocks, 256, 0, stream>>>(in, out);
}

// Round 19
// 45.255 us; speedup vs baseline: 1.0243x; 1.0243x over previous
//
#include <hip/hip_runtime.h>

#define BB 8
#define HH 512
#define WW 512
#define HW (HH * WW)

typedef float f32x2 __attribute__((ext_vector_type(2)));
typedef float f32x4 __attribute__((ext_vector_type(4)));

__device__ __forceinline__ int reflect512(int v) {
    v = v < 0 ? -v : v;
    return v >= 512 ? 1022 - v : v;
}

// unnormalized 1-D spatial gaussian (sigma=21); out-of-window -> 0 (mask)
__device__ __forceinline__ float swx(int dx) {
    const float SW[7] = {0.98984784f, 0.99547514f, 0.99886688f, 1.0f,
                         0.99886688f, 0.99547514f, 0.98984784f};
    return (dx < -3 || dx > 3) ? 0.0f : SW[dx + 3];
}

// exp(-0.005*d2) ~= 1 + C1*d2 + C2*d2^2, |err| <= 1.5e-5 for d<=3 (R5-proven)
#define C1S (-5.0e-3f)
#define C2S (1.25e-5f)

// one staged row: 9 dwordx4 -> 6 column pairs x 3 channels
__device__ __forceinline__ void loadrow(const float* __restrict__ p0,
                                        const float* __restrict__ p1,
                                        const float* __restrict__ p2,
                                        int rb, f32x2 (&q)[6][3]) {
    f32x4 a0 = *(const f32x4*)(p0 + rb), b0 = *(const f32x4*)(p0 + rb + 4),
          c0 = *(const f32x4*)(p0 + rb + 8);
    f32x4 a1 = *(const f32x4*)(p1 + rb), b1 = *(const f32x4*)(p1 + rb + 4),
          c1 = *(const f32x4*)(p1 + rb + 8);
    f32x4 a2 = *(const f32x4*)(p2 + rb), b2 = *(const f32x4*)(p2 + rb + 4),
          c2 = *(const f32x4*)(p2 + rb + 8);
    q[0][0]=(f32x2){a0.x,a0.y}; q[1][0]=(f32x2){a0.z,a0.w};
    q[2][0]=(f32x2){b0.x,b0.y}; q[3][0]=(f32x2){b0.z,b0.w};
    q[4][0]=(f32x2){c0.x,c0.y}; q[5][0]=(f32x2){c0.z,c0.w};
    q[0][1]=(f32x2){a1.x,a1.y}; q[1][1]=(f32x2){a1.z,a1.w};
    q[2][1]=(f32x2){b1.x,b1.y}; q[3][1]=(f32x2){b1.z,b1.w};
    q[4][1]=(f32x2){c1.x,c1.y}; q[5][1]=(f32x2){c1.z,c1.w};
    q[0][2]=(f32x2){a2.x,a2.y}; q[1][2]=(f32x2){a2.z,a2.w};
    q[2][2]=(f32x2){b2.x,b2.y}; q[3][2]=(f32x2){b2.z,b2.w};
    q[4][2]=(f32x2){c2.x,c2.y}; q[5][2]=(f32x2){c2.z,c2.w};
}

// all 16 active (k, pair) taps of one output row; wj constant-folds at inline
__device__ __forceinline__ void rowtaps(float wj, const f32x2 (&q)[6][3],
                                        const float (&ccr)[3][4],
                                        f32x2 (&ar)[4][4]) {
    const float wjC2 = wj * C2S, wjC1 = wj * C1S;
    const f32x2 A2 = {wjC2, wjC2}, A1 = {wjC1, wjC1}, A0 = {wj, wj};
    #pragma unroll
    for (int k = 0; k < 4; ++k) {
        #pragma unroll
        for (int P = 0; P < 6; ++P) {
            const float wlo = swx(2 * P - 4 - k);
            const float whi = swx(2 * P - 3 - k);
            if (wlo == 0.f && whi == 0.f) continue;      // pruned (compile-time)
            const f32x2 WC = {wlo, whi};
            const float k0 = ccr[0][k], k1 = ccr[1][k], k2 = ccr[2][k];
            float dlo = fabsf(q[P][0].x - k0) + fabsf(q[P][1].x - k1) + fabsf(q[P][2].x - k2);
            float dhi = fabsf(q[P][0].y - k0) + fabsf(q[P][1].y - k1) + fabsf(q[P][2].y - k2);
            f32x2 dp = {dlo, dhi};
            f32x2 z  = dp * dp;                          // pk_mul
            f32x2 w  = ((A2 * z + A1) * z + A0) * WC;    // 2x pk_fma + pk_mul
            ar[k][0] += w * q[P][0];
            ar[k][1] += w * q[P][1];
            ar[k][2] += w * q[P][2];
            ar[k][3] += w;
        }
    }
}

// R17 geometry (2 rows x 4 cols = 8 px/thread, dwordx4 window loads) plus
// ENFORCED next-row prefetch: loads of staged row r+1 are issued, then
// sched_barrier(0) pins them before row r's taps — the compiler cannot
// re-sink them to their uses (R15's declared dbuf collapsed; VGPR 68).
__global__ __launch_bounds__(256) void bilateral_r19(const float* __restrict__ in,
                                                     float* __restrict__ out) {
    const int blk = blockIdx.x;
    if (blk >= 128) {
        const int iblk = blk - 128;
        // XCD swizzle: iblk%8 = XCD -> XCD k walks image k in y-order
        const int b   = iblk & 7;
        const int rp2 = iblk >> 3;                // 0..127
        const int sub = threadIdx.x >> 7;         // 0..1
        const int c   = threadIdx.x & 127;
        if (c == 0 || c == 127) return;           // border blocks handle those
        const int y0 = rp2 * 4 + sub * 2;         // rows y0, y0+1
        const int x0 = 4 * c;
        const int xl = x0 - 4;                    // 16B-aligned

        const float* __restrict__ p0 = in + (size_t)(3 * b) * HW;
        const float* __restrict__ p1 = p0 + HW;
        const float* __restrict__ p2 = p1 + HW;

        float cc0[3][4], cc1[3][4];
        {
            const int cb = y0 * WW + x0;
            f32x4 C0 = *(const f32x4*)(p0 + cb);
            f32x4 C1 = *(const f32x4*)(p1 + cb);
            f32x4 C2 = *(const f32x4*)(p2 + cb);
            cc0[0][0]=C0.x; cc0[0][1]=C0.y; cc0[0][2]=C0.z; cc0[0][3]=C0.w;
            cc0[1][0]=C1.x; cc0[1][1]=C1.y; cc0[1][2]=C1.z; cc0[1][3]=C1.w;
            cc0[2][0]=C2.x; cc0[2][1]=C2.y; cc0[2][2]=C2.z; cc0[2][3]=C2.w;
            f32x4 D0 = *(const f32x4*)(p0 + cb + WW);
            f32x4 D1 = *(const f32x4*)(p1 + cb + WW);
            f32x4 D2 = *(const f32x4*)(p2 + cb + WW);
            cc1[0][0]=D0.x; cc1[0][1]=D0.y; cc1[0][2]=D0.z; cc1[0][3]=D0.w;
            cc1[1][0]=D1.x; cc1[1][1]=D1.y; cc1[1][2]=D1.z; cc1[1][3]=D1.w;
            cc1[2][0]=D2.x; cc1[2][1]=D2.y; cc1[2][2]=D2.z; cc1[2][3]=D2.w;
        }

        f32x2 acc0[4][4], acc1[4][4];
        #pragma unroll
        for (int k = 0; k < 4; ++k)
            #pragma unroll
            for (int v = 0; v < 4; ++v) {
                acc0[k][v] = (f32x2){0.f, 0.f};
                acc1[k][v] = (f32x2){0.f, 0.f};
            }

        const float SWT[7] = {0.98984784f, 0.99547514f, 0.99886688f, 1.0f,
                              0.99886688f, 0.99547514f, 0.98984784f};

        f32x2 qa[6][3], qb[6][3];
        loadrow(p0, p1, p2, reflect512(y0 - 3) * WW + xl, qa);   // staged r=0

        // staged row r feeds: out-row0 with dy=r (r<=6), out-row1 with dy=r-1 (r>=1)
        #define STEP(R, QC, QN)                                                   \
            if ((R) < 7)                                                          \
                loadrow(p0, p1, p2, reflect512(y0 + (R) - 2) * WW + xl, QN);      \
            __builtin_amdgcn_sched_barrier(0);                                    \
            if ((R) <= 6) rowtaps(SWT[(R)], QC, cc0, acc0);                       \
            if ((R) >= 1) rowtaps(SWT[(R) - 1], QC, cc1, acc1);

        STEP(0, qa, qb)
        STEP(1, qb, qa)
        STEP(2, qa, qb)
        STEP(3, qb, qa)
        STEP(4, qa, qb)
        STEP(5, qb, qa)
        STEP(6, qa, qb)
        STEP(7, qb, qa)
        #undef STEP

        #pragma unroll
        for (int row = 0; row < 2; ++row) {
            f32x2 (&ar)[4][4] = row ? acc1 : acc0;
            f32x4 o0, o1, o2;
            #pragma unroll
            for (int k = 0; k < 4; ++k) {
                const float inv = 1.0f / (ar[k][3].x + ar[k][3].y);
                const float v0 = (ar[k][0].x + ar[k][0].y) * inv;
                const float v1 = (ar[k][1].x + ar[k][1].y) * inv;
                const float v2 = (ar[k][2].x + ar[k][2].y) * inv;
                if (k == 0) { o0.x = v0; o1.x = v1; o2.x = v2; }
                if (k == 1) { o0.y = v0; o1.y = v1; o2.y = v2; }
                if (k == 2) { o0.z = v0; o1.z = v1; o2.z = v2; }
                if (k == 3) { o0.w = v0; o1.w = v1; o2.w = v2; }
            }
            size_t ob = (size_t)(3 * b) * HW + (size_t)(y0 + row) * WW + x0;
            *(f32x4*)(out + ob)        = o0;
            *(f32x4*)(out + ob + HW)   = o1;
            *(f32x4*)(out + ob + 2*HW) = o2;
        }
    } else {
        // ---- border path FIRST: columns {0..3, 508..511}, all rows/batches ----
        int idx  = blk * 256 + threadIdx.x;   // exactly 32768
        int ci   = idx & 7;
        int rest = idx >> 3;
        int y = rest & 511;
        int b = rest >> 9;
        int x = ci < 4 ? ci : 504 + ci;

        const float* __restrict__ p0 = in + (size_t)(3 * b) * HW;
        const float* __restrict__ p1 = p0 + HW;
        const float* __restrict__ p2 = p1 + HW;
        int cidx = y * WW + x;
        float c0 = p0[cidx], c1 = p1[cidx], c2 = p2[cidx];
        float n0 = 0.f, n1 = 0.f, n2 = 0.f, dn = 0.f;
        #pragma unroll
        for (int dy = 0; dy < 7; ++dy) {
            int rbase = reflect512(y + dy - 3) * WW;
            float wy = swx(dy - 3);
            #pragma unroll
            for (int dx = 0; dx < 7; ++dx) {
                int o = rbase + reflect512(x + dx - 3);
                float q0 = p0[o], q1 = p1[o], q2 = p2[o];
                float d  = fabsf(q0 - c0) + fabsf(q1 - c1) + fabsf(q2 - c2);
                float d2 = d * d;
                float w  = wy * swx(dx - 3) * fmaf(fmaf(C2S, d2, C1S), d2, 1.0f);
                n0 += w * q0; n1 += w * q1; n2 += w * q2; dn += w;
            }
        }
        float inv = 1.0f / dn;
        size_t ob = (size_t)(3 * b) * HW + cidx;
        out[ob] = n0 * inv; out[ob + HW] = n1 * inv; out[ob + 2 * HW] = n2 * inv;
    }
}

extern "C" void kernel_launch(void* const* d_in, const int* in_sizes, int n_in,
                              void* d_out, int out_size, void* d_ws, size_t ws_size,
                              hipStream_t stream) {
    const float* in = (const float*)d_in[0];
    float* out = (float*)d_out;
    // 128 border blocks first, then 1024 interior (8 img x 128 row-quads)
    int blocks = 128 + 1024;
    bilateral_r19<<<blocks, 256, 0, stream>>>(in, out);
}

// Round 20
// 42.736 us; speedup vs baseline: 1.0846x; 1.0589x over previous
//
#include <hip/hip_runtime.h>

#define BB 8
#define HH 512
#define WW 512
#define HW (HH * WW)

typedef float f32x2 __attribute__((ext_vector_type(2)));
typedef float f32x4 __attribute__((ext_vector_type(4)));

__device__ __forceinline__ int reflect512(int v) {
    v = v < 0 ? -v : v;
    return v >= 512 ? 1022 - v : v;
}

// unnormalized 1-D spatial gaussian (sigma=21); out-of-window -> 0 (mask)
__device__ __forceinline__ float swx(int dx) {
    const float SW[7] = {0.98984784f, 0.99547514f, 0.99886688f, 1.0f,
                         0.99886688f, 0.99547514f, 0.98984784f};
    return (dx < -3 || dx > 3) ? 0.0f : SW[dx + 3];
}

// exp(-0.005*d2) ~= 1 + C1*d2 + C2*d2^2, |err| <= 1.5e-5 for d<=3 (R5-proven)
#define C1S (-5.0e-3f)
#define C2S (1.25e-5f)

// CHAMPION (R17, 42.8 us). 2 rows x 4 cols = 8 px/thread; window rows loaded
// once as 3x dwordx4 per channel feed both output rows and all 4 centers.
// Spatial weights folded fully into per-tap poly coeffs (compile-time);
// inactive (pair,center) combos pruned at compile time. Stores dwordx4.
// Plateau notes (R18/R19): VALU-pipe floor ~26 us (v_pk_f32 is ALU-cycle-
// neutral on CDNA); issue density ~60% is structural — wave supply, L2
// locality, I$ size, and enforced prefetch each isolated and refuted.
__global__ __launch_bounds__(256) void bilateral_q8(const float* __restrict__ in,
                                                    float* __restrict__ out) {
    const int blk = blockIdx.x;
    if (blk < 1024) {
        // XCD swizzle: blk%8 = XCD -> XCD k walks image k in y-order (R13/R14)
        const int b   = blk & 7;
        const int rp2 = blk >> 3;                 // 0..127
        const int sub = threadIdx.x >> 7;         // 0..1
        const int c   = threadIdx.x & 127;        // col group
        if (c == 0 || c == 127) return;           // cols 0-3,508-511 -> border path
        const int y0 = rp2 * 4 + sub * 2;         // rows y0, y0+1
        const int x0 = 4 * c;                     // cols x0..x0+3 (4..504)
        const int xl = x0 - 4;                    // leftmost loaded col, 16B aligned

        const float* __restrict__ p0 = in + (size_t)(3 * b) * HW;
        const float* __restrict__ p1 = p0 + HW;
        const float* __restrict__ p2 = p1 + HW;

        // centers cc[row][ch][k] for 4 pixels per row
        float cc[2][3][4];
        #pragma unroll
        for (int row = 0; row < 2; ++row) {
            const int cb = (y0 + row) * WW + x0;
            f32x4 C0 = *(const f32x4*)(p0 + cb);
            f32x4 C1 = *(const f32x4*)(p1 + cb);
            f32x4 C2 = *(const f32x4*)(p2 + cb);
            cc[row][0][0]=C0.x; cc[row][0][1]=C0.y; cc[row][0][2]=C0.z; cc[row][0][3]=C0.w;
            cc[row][1][0]=C1.x; cc[row][1][1]=C1.y; cc[row][1][2]=C1.z; cc[row][1][3]=C1.w;
            cc[row][2][0]=C2.x; cc[row][2][1]=C2.y; cc[row][2][2]=C2.z; cc[row][2][3]=C2.w;
        }

        // acc[row][k][v], v = ch0,ch1,ch2,den — packed column pairs
        f32x2 acc[2][4][4];
        #pragma unroll
        for (int row = 0; row < 2; ++row)
            #pragma unroll
            for (int k = 0; k < 4; ++k)
                #pragma unroll
                for (int v = 0; v < 4; ++v) acc[row][k][v] = (f32x2){0.f, 0.f};

        const float SWT[7] = {0.98984784f, 0.99547514f, 0.99886688f, 1.0f,
                              0.99886688f, 0.99547514f, 0.98984784f};

        #pragma unroll
        for (int r = 0; r < 8; ++r) {             // staged rows y0-3 .. y0+4
            const int rb = reflect512(y0 - 3 + r) * WW + xl;
            f32x4 L0a = *(const f32x4*)(p0 + rb);
            f32x4 L0b = *(const f32x4*)(p0 + rb + 4);
            f32x4 L0c = *(const f32x4*)(p0 + rb + 8);
            f32x4 L1a = *(const f32x4*)(p1 + rb);
            f32x4 L1b = *(const f32x4*)(p1 + rb + 4);
            f32x4 L1c = *(const f32x4*)(p1 + rb + 8);
            f32x4 L2a = *(const f32x4*)(p2 + rb);
            f32x4 L2b = *(const f32x4*)(p2 + rb + 4);
            f32x4 L2c = *(const f32x4*)(p2 + rb + 8);
            // column pairs q[P][ch], P=0..5 over cols xl+2P, xl+2P+1
            f32x2 q[6][3];
            q[0][0]=(f32x2){L0a.x,L0a.y}; q[1][0]=(f32x2){L0a.z,L0a.w};
            q[2][0]=(f32x2){L0b.x,L0b.y}; q[3][0]=(f32x2){L0b.z,L0b.w};
            q[4][0]=(f32x2){L0c.x,L0c.y}; q[5][0]=(f32x2){L0c.z,L0c.w};
            q[0][1]=(f32x2){L1a.x,L1a.y}; q[1][1]=(f32x2){L1a.z,L1a.w};
            q[2][1]=(f32x2){L1b.x,L1b.y}; q[3][1]=(f32x2){L1b.z,L1b.w};
            q[4][1]=(f32x2){L1c.x,L1c.y}; q[5][1]=(f32x2){L1c.z,L1c.w};
            q[0][2]=(f32x2){L2a.x,L2a.y}; q[1][2]=(f32x2){L2a.z,L2a.w};
            q[2][2]=(f32x2){L2b.x,L2b.y}; q[3][2]=(f32x2){L2b.z,L2b.w};
            q[4][2]=(f32x2){L2c.x,L2c.y}; q[5][2]=(f32x2){L2c.z,L2c.w};

            #pragma unroll
            for (int row = 0; row < 2; ++row) {
                const int dy = r - row;           // window row index 0..6
                if (dy < 0 || dy > 6) continue;   // statically eliminated
                const float wj = SWT[dy];
                #pragma unroll
                for (int k = 0; k < 4; ++k) {
                    #pragma unroll
                    for (int P = 0; P < 6; ++P) {
                        const float wlo = swx(2 * P - 4 - k);
                        const float whi = swx(2 * P - 3 - k);
                        if (wlo == 0.f && whi == 0.f) continue;  // pruned
                        // fully folded coeffs (compile-time constants)
                        const f32x2 A2c = {wj * wlo * C2S, wj * whi * C2S};
                        const f32x2 A1c = {wj * wlo * C1S, wj * whi * C1S};
                        const f32x2 A0c = {wj * wlo,       wj * whi};
                        const float k0 = cc[row][0][k], k1 = cc[row][1][k], k2 = cc[row][2][k];
                        float dlo = fabsf(q[P][0].x - k0) + fabsf(q[P][1].x - k1) +
                                    fabsf(q[P][2].x - k2);
                        float dhi = fabsf(q[P][0].y - k0) + fabsf(q[P][1].y - k1) +
                                    fabsf(q[P][2].y - k2);
                        f32x2 dp = {dlo, dhi};
                        f32x2 z  = dp * dp;                  // pk_mul
                        f32x2 w  = (A2c * z + A1c) * z + A0c; // 2x pk_fma
                        acc[row][k][0] += w * q[P][0];
                        acc[row][k][1] += w * q[P][1];
                        acc[row][k][2] += w * q[P][2];
                        acc[row][k][3] += w;
                    }
                }
            }
        }

        #pragma unroll
        for (int row = 0; row < 2; ++row) {
            f32x4 o0, o1, o2;
            #pragma unroll
            for (int k = 0; k < 4; ++k) {
                const float inv = 1.0f / (acc[row][k][3].x + acc[row][k][3].y);
                const float v0 = (acc[row][k][0].x + acc[row][k][0].y) * inv;
                const float v1 = (acc[row][k][1].x + acc[row][k][1].y) * inv;
                const float v2 = (acc[row][k][2].x + acc[row][k][2].y) * inv;
                if (k == 0) { o0.x = v0; o1.x = v1; o2.x = v2; }
                if (k == 1) { o0.y = v0; o1.y = v1; o2.y = v2; }
                if (k == 2) { o0.z = v0; o1.z = v1; o2.z = v2; }
                if (k == 3) { o0.w = v0; o1.w = v1; o2.w = v2; }
            }
            size_t ob = (size_t)(3 * b) * HW + (size_t)(y0 + row) * WW + x0;
            *(f32x4*)(out + ob)          = o0;
            *(f32x4*)(out + ob + HW)     = o1;
            *(f32x4*)(out + ob + 2*HW)   = o2;
        }
    } else {
        // ---- border path: columns {0,1,2,3,508,509,510,511} ----
        int idx  = (blk - 1024) * 256 + threadIdx.x;   // exactly 32768
        int ci   = idx & 7;
        int rest = idx >> 3;
        int y = rest & 511;
        int b = rest >> 9;
        int x = ci < 4 ? ci : 504 + ci;

        const float* __restrict__ p0 = in + (size_t)(3 * b) * HW;
        const float* __restrict__ p1 = p0 + HW;
        const float* __restrict__ p2 = p1 + HW;
        int cidx = y * WW + x;
        float c0 = p0[cidx], c1 = p1[cidx], c2 = p2[cidx];
        float n0 = 0.f, n1 = 0.f, n2 = 0.f, dn = 0.f;
        #pragma unroll
        for (int dy = 0; dy < 7; ++dy) {
            int rbase = reflect512(y + dy - 3) * WW;
            float wy = swx(dy - 3);
            #pragma unroll
            for (int dx = 0; dx < 7; ++dx) {
                int o = rbase + reflect512(x + dx - 3);
                float q0 = p0[o], q1 = p1[o], q2 = p2[o];
                float d  = fabsf(q0 - c0) + fabsf(q1 - c1) + fabsf(q2 - c2);
                float d2 = d * d;
                float w  = wy * swx(dx - 3) * fmaf(fmaf(C2S, d2, C1S), d2, 1.0f);
                n0 += w * q0; n1 += w * q1; n2 += w * q2; dn += w;
            }
        }
        float inv = 1.0f / dn;
        size_t ob = (size_t)(3 * b) * HW + cidx;
        out[ob] = n0 * inv; out[ob + HW] = n1 * inv; out[ob + 2 * HW] = n2 * inv;
    }
}

extern "C" void kernel_launch(void* const* d_in, const int* in_sizes, int n_in,
                              void* d_out, int out_size, void* d_ws, size_t ws_size,
                              hipStream_t stream) {
    const float* in = (const float*)d_in[0];
    float* out = (float*)d_out;
    // 1024 interior blocks (8 img x 128 row-quads) + 128 border blocks
    int blocks = 1024 + 128;
    bilateral_q8<<<blocks, 256, 0, stream>>>(in, out);
}